// Round 3
// baseline (186.379 us; speedup 1.0000x reference)
//
#include <hip/hip_runtime.h>
#include <hip/hip_fp16.h>

// DiffusionConv: out = x@Tf0 + Px@(Tb0+Tb1) + P2x@(Tf1+Tb2) + P3x@Tf2
// R17: eliminate the pedges/build preprocessing chain. scatter_kernel now
// builds bkt DIRECTLY with returning global atomics (slot=atomicAdd(cnt[r]));
// L2 write-back absorbs the 4B scatter. build_kernel deleted (-7.2MB read,
// -6.4MB pedges write, -12.8MB full-region bkt dump, -800K LDS atomics).
// dinv computed by a tiny quarter-wave-reduce kernel. Props + fused MFMA
// gemm are byte-identical to the verified R16 versions (same bkt layout;
// only slot order differs -> fp reorder noise only).

#define N_NODES 50000
#define N_EDGES 800000
#define C 64
#define CAP 64          // bucket capacity; rows ~ Poisson(16), P(>64) ~ 2e-18
#define EB 196          // edge blocks: 196*1024 threads * 4 edges = 802816
#define XH_BLOCKS 782   // ceil(800000 float4 chunks / 1024)
#define CW_BLOCKS 16    // 16384 weight elems / 1024

typedef _Float16 half8 __attribute__((ext_vector_type(8)));
typedef float f32x4 __attribute__((ext_vector_type(4)));

// Fused: blocks [0,EB): direct-scatter into bkt; [EB,EB+XH): x fp32->fp16;
// [EB+XH,..): combined weights -> fp16 transposed whc[j][co][ci]
__global__ __launch_bounds__(1024) void scatter_kernel(
        const int* __restrict__ row, const int* __restrict__ col,
        const float* __restrict__ w, int* __restrict__ cnt,
        unsigned int* __restrict__ bkt,
        const float* __restrict__ x, __half* __restrict__ xh,
        const float* __restrict__ tf, const float* __restrict__ tb,
        _Float16* __restrict__ whc) {
    const int tid = threadIdx.x;
    if (blockIdx.x >= EB + XH_BLOCKS) {
        int idx = (blockIdx.x - EB - XH_BLOCKS) * 1024 + tid;  // < 16384
        int j = idx >> 12;
        int rem = idx & 4095;   // ci*64 + co
        int ci = rem >> 6;
        int co = rem & 63;
        float v;
        if (j == 0)      v = tf[rem];                         // Tf0
        else if (j == 1) v = tb[rem] + tb[4096 + rem];        // Tb0 + Tb1
        else if (j == 2) v = tf[4096 + rem] + tb[8192 + rem]; // Tf1 + Tb2
        else             v = tf[8192 + rem];                  // Tf2
        whc[(j << 12) + (co << 6) + ci] = (_Float16)v;        // transposed
        return;
    }
    if (blockIdx.x >= EB) {
        int i = (blockIdx.x - EB) * 1024 + tid;
        if (i < N_NODES * C / 4) {
            float4 v = ((const float4*)x)[i];
            union { float2 f2; __half2 h2[2]; } u;
            u.h2[0] = __floats2half2_rn(v.x, v.y);
            u.h2[1] = __floats2half2_rn(v.z, v.w);
            ((float2*)xh)[i] = u.f2;
        }
        return;
    }
    // direct-scatter phase: 4 edges per thread, vectorized meta loads
    int e0 = (blockIdx.x * 1024 + tid) * 4;
    if (e0 < N_EDGES) {
        int4   r4 = *(const int4*)(row + e0);
        int4   c4 = *(const int4*)(col + e0);
        float4 w4 = *(const float4*)(w + e0);
        int rr[4] = {r4.x, r4.y, r4.z, r4.w};
        int cc[4] = {c4.x, c4.y, c4.z, c4.w};
        float ww[4] = {w4.x, w4.y, w4.z, w4.w};
#pragma unroll
        for (int i = 0; i < 4; ++i) {
            unsigned int wh =
                (unsigned int)__half_as_ushort(__float2half_rn(ww[i]));
            int slot = atomicAdd(&cnt[rr[i]], 1);
            if (slot < CAP)
                bkt[((size_t)rr[i] << 6) + slot] =
                    ((unsigned int)cc[i] << 16) | wh;
        }
    }
}

// dinv[i] = rsqrt(sum of half-rounded weights of row i). Quarter layout:
// wave handles 4 nodes; lane ql (0-15) reads strided entries, 16-lane
// shfl_xor tree reduces; lane 0 of each quarter writes.
__global__ __launch_bounds__(256) void dinv_kernel(
        const int* __restrict__ cnt, const unsigned int* __restrict__ bkt,
        float* __restrict__ dinv) {
    const int tid = threadIdx.x;
    const int wib = tid >> 6;
    const int lane = tid & 63;
    const int q = lane >> 4;
    const int ql = lane & 15;
    const int node = (blockIdx.x << 4) + (wib << 2) + q;   // < 50000 exactly
    int m = min(cnt[node], CAP);
    size_t base = (size_t)node << 6;
    float sum = 0.f;
#pragma unroll
    for (int s = 0; s < 4; ++s) {
        int idx = (s << 4) + ql;
        if (idx < m)
            sum += __half2float(__ushort_as_half(
                (unsigned short)(bkt[base + idx] & 0xFFFFu)));
    }
    sum += __shfl_xor(sum, 1);
    sum += __shfl_xor(sum, 2);
    sum += __shfl_xor(sum, 4);
    sum += __shfl_xor(sum, 8);
    if (ql == 0) dinv[node] = (sum > 0.f) ? rsqrtf(sum) : 0.f;
}

// 4 nodes per wave: quarter q owns node wave*4+q; lane ql (0-15) holds
// channels 4ql..4ql+3. Bucket meta prefetched upfront (<=4 entries/lane).
// FIXW (prop1): n = w * dinv[col], written back into bkt so later props
//   read the normalized weight directly (no dinv gather).
// FUSE_GEMM (prop3): block's 16 rows = one MFMA tile; tC rows staged in LDS
//   (stride 72 halves => conflict-light ds_read_b128), then each wave
//   computes a 16-col block of out = xh@W0 + tA@W1 + tB@W2 + tC@W3.
template <bool FIXW, bool FUSE_GEMM>
__global__ __launch_bounds__(256) void prop_kernel(
        const __half* __restrict__ xin, __half* __restrict__ xout,
        const int* __restrict__ cnt, unsigned int* __restrict__ bkt,
        const float* __restrict__ dinv,
        const __half* __restrict__ x0, const __half* __restrict__ x1,
        const _Float16* __restrict__ whc, float* __restrict__ out) {
    const int tid = threadIdx.x;
    const int wib = tid >> 6;
    const int lane = tid & 63;
    const int q = lane >> 4;
    const int ql = lane & 15;
    const int node = (blockIdx.x << 4) + (wib << 2) + q;  // < 50000 always
    int m = min(cnt[node], CAP);
    int base = node << 6;
    // prefetch all (<=4) strided bucket entries for this lane
    int cj[4];
    float nj[4];
#pragma unroll
    for (int s = 0; s < 4; ++s) {
        int idx = (s << 4) + ql;
        cj[s] = 0;
        nj[s] = 0.f;
        if (idx < m) {
            unsigned int b = bkt[base + idx];
            int c = (int)(b >> 16);
            cj[s] = c << 6;                                // half-elem row offset
            float wv = __half2float(__ushort_as_half((unsigned short)(b & 0xFFFFu)));
            if constexpr (FIXW) {
                float nn = wv * dinv[c];
                nj[s] = nn;
                bkt[base + idx] = ((unsigned int)c << 16) |
                    (unsigned int)__half_as_ushort(__float2half_rn(nn));
            } else {
                nj[s] = wv;
            }
        }
    }
    float ax = 0.f, ay = 0.f, az = 0.f, aw = 0.f;
#pragma unroll
    for (int s = 0; s < 4; ++s) {
        int cb = s << 4;
        if (cb >= m) break;
        int rem = m - cb;
        if (rem > 16) rem = 16;
        int mm = (rem + 7) & ~7;    // padded lanes carry cj=0,nj=0
        for (int jo = 0; jo < mm; jo += 8) {
            int cs[8];
            float ns[8];
            float2 vs[8];
#pragma unroll
            for (int t = 0; t < 8; ++t) {
                cs[t] = __shfl(cj[s], (q << 4) + jo + t);
                ns[t] = __shfl(nj[s], (q << 4) + jo + t);
            }
#pragma unroll
            for (int t = 0; t < 8; ++t)
                vs[t] = *(const float2*)(xin + cs[t] + (ql << 2));
#pragma unroll
            for (int t = 0; t < 8; ++t) {
                const __half2* hp = (const __half2*)&vs[t];
                float2 a = __half22float2(hp[0]);
                float2 b = __half22float2(hp[1]);
                ax += ns[t] * a.x;
                ay += ns[t] * a.y;
                az += ns[t] * b.x;
                aw += ns[t] * b.y;
            }
        }
    }
    float dr = dinv[node];
    union { float2 f2; __half2 h2[2]; } u;
    u.h2[0] = __floats2half2_rn(dr * ax, dr * ay);
    u.h2[1] = __floats2half2_rn(dr * az, dr * aw);
    if constexpr (!FUSE_GEMM) {
        *(float2*)(xout + ((size_t)node << 6) + (ql << 2)) = u.f2;
    } else {
        __shared__ _Float16 tcl[16 * 72];   // 16 rows, stride 72 halves (2.3KB)
        // row r_loc = wib*4+q, channels 4ql..4ql+3
        *(float2*)(void*)&tcl[((wib << 2) + q) * 72 + (ql << 2)] = u.f2;
        __syncthreads();
        // ---- fused MFMA GEMM for this block's 16-row tile ----
        // A-frag: A[m=lane&15][k=quad*8+i]; B-frag: B[k][n=lane&15] from
        // transposed whc[j][n][k]; C/D: col=lane&15, row=quad*4+reg.
        // wave wib handles output cols [16*wib, 16*wib+16).
        const int mbase = blockIdx.x << 4;
        const __half* gsrc[3] = {x0, x1, xin};   // xh, tA, tB
        const size_t abase = ((size_t)(mbase + ql) << 6) + (q << 3);
        f32x4 acc = {};
#pragma unroll
        for (int j = 0; j < 4; ++j) {
#pragma unroll
            for (int kk = 0; kk < 64; kk += 32) {
                half8 af;
                if (j < 3)
                    af = *(const half8*)(const void*)(gsrc[j] + abase + kk);
                else
                    af = *(const half8*)(const void*)&tcl[ql * 72 + (q << 3) + kk];
                const _Float16* wb = whc + (j << 12) + (((wib << 4) + ql) << 6)
                                         + (q << 3) + kk;
                half8 bf = *(const half8*)(const void*)wb;
                acc = __builtin_amdgcn_mfma_f32_16x16x32_f16(af, bf, acc, 0, 0, 0);
            }
        }
#pragma unroll
        for (int i = 0; i < 4; ++i) {
            int r = mbase + (q << 2) + i;
            out[((size_t)r << 6) + (wib << 4) + ql] = acc[i];
        }
    }
}

extern "C" void kernel_launch(void* const* d_in, const int* in_sizes, int n_in,
                              void* d_out, int out_size, void* d_ws, size_t ws_size,
                              hipStream_t stream) {
    const float* x  = (const float*)d_in[0];
    const int*   ei = (const int*)d_in[1];   // row = ei[0..E), col = ei[E..2E)
    const float* ew = (const float*)d_in[2];
    const float* tf = (const float*)d_in[3];
    const float* tb = (const float*)d_in[4];
    float* out = (float*)d_out;

    const int* row = ei;
    const int* col = ei + N_EDGES;

    // workspace layout (4B words), total ~39 MB. cnt FIRST (one memset).
    const int NROWS_PAD = 50176;
    float* ws = (float*)d_ws;
    size_t off = 0;
    int*    cnt  = (int*)(ws + off); off += NROWS_PAD;
    float*  dinv = ws + off; off += NROWS_PAD;
    unsigned int* bkt = (unsigned int*)(ws + off); off += (size_t)NROWS_PAD * CAP;
    __half* xh   = (__half*)(ws + off); off += (size_t)N_NODES * C / 2;
    __half* tA   = (__half*)(ws + off); off += (size_t)N_NODES * C / 2;
    __half* tB   = (__half*)(ws + off); off += (size_t)N_NODES * C / 2;
    __half* tC   = (__half*)(ws + off); off += (size_t)N_NODES * C / 2;
    _Float16* whc = (_Float16*)(ws + off); off += 4 * 64 * 64 / 2;

    hipMemsetAsync(cnt, 0, NROWS_PAD * sizeof(int), stream);

    scatter_kernel<<<EB + XH_BLOCKS + CW_BLOCKS, 1024, 0, stream>>>(
        row, col, ew, cnt, bkt, x, xh, tf, tb, whc);

    const int PB = N_NODES / 16;   // 3125 blocks, 16 nodes each (exact)
    dinv_kernel<<<PB, 256, 0, stream>>>(cnt, bkt, dinv);

    prop_kernel<true,  false><<<PB, 256, 0, stream>>>(
        xh, tA, cnt, bkt, dinv, nullptr, nullptr, nullptr, nullptr);   // tx1
    prop_kernel<false, false><<<PB, 256, 0, stream>>>(
        tA, tB, cnt, bkt, dinv, nullptr, nullptr, nullptr, nullptr);   // tx2
    prop_kernel<false, true><<<PB, 256, 0, stream>>>(
        tB, tC, cnt, bkt, dinv, xh, tA, whc, out);                     // tx3+gemm
}

// Round 4
// 158.904 us; speedup vs baseline: 1.1729x; 1.1729x over previous
//
#include <hip/hip_runtime.h>
#include <hip/hip_fp16.h>

// DiffusionConv: out = x@Tf0 + Px@(Tb0+Tb1) + P2x@(Tf1+Tb2) + P3x@Tf2
// R18: revert R17's direct-atomic scatter (48us: 800K returning global
// atomics + 4B cross-XCD scatter -> 55MB write amplification). Back to the
// verified R16 4-kernel pipeline, with two scatter-chain fixes:
//  (a) EPB 2048 -> 8192: per-block partition runs grow 80B -> 336B, 4x fewer
//      cross-XCD shared lines in pedges, 4x fewer percur reservation rounds.
//  (b) build dumps only used bucket slots (ceil(m/4) uint4 per row): write
//      3.4MB instead of 12.8MB; rows are 256B-aligned so lines stay full.
// Props + fused MFMA gemm byte-identical to verified R16.

#define N_NODES 50000
#define N_EDGES 800000
#define C 64
#define CAP 64          // bucket capacity; rows ~ Poisson(16), P(>64) ~ 2e-18
#define NPART 196       // partitions of 256 rows: p = r >> 8
#define CAPP 4608       // edges per partition region; mean 4096, +8 sigma
#define EPB 8192        // edges per block in scatter2 (R18: back to 8192)
#define NEB 98          // ceil(800000/8192)
#define XH_BLOCKS 782   // ceil(800000 float4 chunks / 1024)
#define CW_BLOCKS 16    // 16384 weight elems / 1024

typedef _Float16 half8 __attribute__((ext_vector_type(8)));
typedef float f32x4 __attribute__((ext_vector_type(4)));

// Fused: blocks [0,NEB): hist+reserve+scatter; [NEB,NEB+XH): x fp32->fp16;
// [NEB+XH,..): combined weights -> fp16 transposed whc[j][co][ci]
__global__ __launch_bounds__(1024) void scatter2_kernel(
        const int* __restrict__ row, const int* __restrict__ col,
        const float* __restrict__ w, int* __restrict__ percur,
        uint2* __restrict__ pedges,
        const float* __restrict__ x, __half* __restrict__ xh,
        const float* __restrict__ tf, const float* __restrict__ tb,
        _Float16* __restrict__ whc) {
    const int tid = threadIdx.x;
    if (blockIdx.x >= NEB + XH_BLOCKS) {
        int idx = (blockIdx.x - NEB - XH_BLOCKS) * 1024 + tid;  // < 16384
        int j = idx >> 12;
        int rem = idx & 4095;   // ci*64 + co
        int ci = rem >> 6;
        int co = rem & 63;
        float v;
        if (j == 0)      v = tf[rem];                         // Tf0
        else if (j == 1) v = tb[rem] + tb[4096 + rem];        // Tb0 + Tb1
        else if (j == 2) v = tf[4096 + rem] + tb[8192 + rem]; // Tf1 + Tb2
        else             v = tf[8192 + rem];                  // Tf2
        whc[(j << 12) + (co << 6) + ci] = (_Float16)v;        // transposed
        return;
    }
    if (blockIdx.x >= NEB) {
        int i = (blockIdx.x - NEB) * 1024 + tid;
        if (i < N_NODES * C / 4) {
            float4 v = ((const float4*)x)[i];
            union { float2 f2; __half2 h2[2]; } u;
            u.h2[0] = __floats2half2_rn(v.x, v.y);
            u.h2[1] = __floats2half2_rn(v.z, v.w);
            ((float2*)xh)[i] = u.f2;
        }
        return;
    }
    __shared__ int h[NPART];
    __shared__ int cur[NPART];
    uint2 ent[8];
    int pp[8];
    if (tid < NPART) h[tid] = 0;
    __syncthreads();
    int base = blockIdx.x * EPB;
#pragma unroll
    for (int i = 0; i < 8; ++i) {
        int e = base + i * 1024 + tid;
        pp[i] = -1;
        if (e < N_EDGES) {
            int r = row[e];
            unsigned int c = (unsigned int)col[e];
            unsigned int wh = (unsigned int)__half_as_ushort(__float2half_rn(w[e]));
            ent[i] = make_uint2((c << 16) | wh, (unsigned int)(r & 255));
            pp[i] = r >> 8;
            atomicAdd(&h[pp[i]], 1);
        }
    }
    __syncthreads();
    if (tid < NPART) cur[tid] = atomicAdd(&percur[tid], h[tid]);
    __syncthreads();
#pragma unroll
    for (int i = 0; i < 8; ++i) {
        if (pp[i] >= 0) {
            int slot = atomicAdd(&cur[pp[i]], 1);
            pedges[(size_t)pp[i] * CAPP + slot] = ent[i];
        }
    }
}

// One block per partition: LDS-bin 256 rows x 64 slots, fuse dinv,
// dump only the used slot prefix per row (uint4 chunks).
__global__ __launch_bounds__(1024) void build_kernel(
        const uint2* __restrict__ pedges, const int* __restrict__ percur,
        unsigned int* __restrict__ bkt, int* __restrict__ cnt,
        float* __restrict__ dinv) {
    __shared__ unsigned int lbuck[256 * CAP];   // 64 KB
    __shared__ int lcnt[256];
    const int tid = threadIdx.x;
    const int p = blockIdx.x;
    if (tid < 256) lcnt[tid] = 0;
    __syncthreads();
    int e = min(percur[p], CAPP);
    const uint2* src = pedges + (size_t)p * CAPP;
    for (int i = tid; i < e; i += 1024) {
        uint2 en = src[i];
        int rl = (int)en.y;
        int slot = atomicAdd(&lcnt[rl], 1);
        if (slot < CAP) lbuck[(rl << 6) + slot] = en.x;
    }
    __syncthreads();
    if (tid < 256) {
        int m = min(lcnt[tid], CAP);
        int g = (p << 8) + tid;
        float sum = 0.f;
        for (int j = 0; j < m; ++j)
            sum += __half2float(__ushort_as_half(
                (unsigned short)(lbuck[(tid << 6) + j] & 0xFFFFu)));
        if (g < N_NODES) {
            cnt[g] = m;
            dinv[g] = (sum > 0.f) ? rsqrtf(sum) : 0.f;
        }
    }
    __syncthreads();
    // sparse dump: 4 threads per row, chunk = tid&3; only ceil(m/4) uint4s
    {
        int r = tid >> 2;
        int ch = tid & 3;
        int m = min(lcnt[r], CAP);
        const uint4* s4 = (const uint4*)&lbuck[r << 6];
        uint4* dst = (uint4*)(bkt + (((size_t)(p << 8) + r) << 6));
        for (int j = ch; (j << 2) < m; j += 4) dst[j] = s4[j];
    }
}

// 4 nodes per wave: quarter q owns node wave*4+q; lane ql (0-15) holds
// channels 4ql..4ql+3. Bucket meta prefetched upfront (<=4 entries/lane).
// FIXW (prop1): n = w * dinv[col], written back into bkt so later props
//   read the normalized weight directly (no dinv gather).
// FUSE_GEMM (prop3): block's 16 rows = one MFMA tile; tC rows staged in LDS
//   (stride 72 halves => conflict-light ds_read_b128), then each wave
//   computes a 16-col block of out = xh@W0 + tA@W1 + tB@W2 + tC@W3.
template <bool FIXW, bool FUSE_GEMM>
__global__ __launch_bounds__(256) void prop_kernel(
        const __half* __restrict__ xin, __half* __restrict__ xout,
        const int* __restrict__ cnt, unsigned int* __restrict__ bkt,
        const float* __restrict__ dinv,
        const __half* __restrict__ x0, const __half* __restrict__ x1,
        const _Float16* __restrict__ whc, float* __restrict__ out) {
    const int tid = threadIdx.x;
    const int wib = tid >> 6;
    const int lane = tid & 63;
    const int q = lane >> 4;
    const int ql = lane & 15;
    const int node = (blockIdx.x << 4) + (wib << 2) + q;  // < 50000 always
    int m = min(cnt[node], CAP);
    int base = node << 6;
    // prefetch all (<=4) strided bucket entries for this lane
    int cj[4];
    float nj[4];
#pragma unroll
    for (int s = 0; s < 4; ++s) {
        int idx = (s << 4) + ql;
        cj[s] = 0;
        nj[s] = 0.f;
        if (idx < m) {
            unsigned int b = bkt[base + idx];
            int c = (int)(b >> 16);
            cj[s] = c << 6;                                // half-elem row offset
            float wv = __half2float(__ushort_as_half((unsigned short)(b & 0xFFFFu)));
            if constexpr (FIXW) {
                float nn = wv * dinv[c];
                nj[s] = nn;
                bkt[base + idx] = ((unsigned int)c << 16) |
                    (unsigned int)__half_as_ushort(__float2half_rn(nn));
            } else {
                nj[s] = wv;
            }
        }
    }
    float ax = 0.f, ay = 0.f, az = 0.f, aw = 0.f;
#pragma unroll
    for (int s = 0; s < 4; ++s) {
        int cb = s << 4;
        if (cb >= m) break;
        int rem = m - cb;
        if (rem > 16) rem = 16;
        int mm = (rem + 7) & ~7;    // padded lanes carry cj=0,nj=0
        for (int jo = 0; jo < mm; jo += 8) {
            int cs[8];
            float ns[8];
            float2 vs[8];
#pragma unroll
            for (int t = 0; t < 8; ++t) {
                cs[t] = __shfl(cj[s], (q << 4) + jo + t);
                ns[t] = __shfl(nj[s], (q << 4) + jo + t);
            }
#pragma unroll
            for (int t = 0; t < 8; ++t)
                vs[t] = *(const float2*)(xin + cs[t] + (ql << 2));
#pragma unroll
            for (int t = 0; t < 8; ++t) {
                const __half2* hp = (const __half2*)&vs[t];
                float2 a = __half22float2(hp[0]);
                float2 b = __half22float2(hp[1]);
                ax += ns[t] * a.x;
                ay += ns[t] * a.y;
                az += ns[t] * b.x;
                aw += ns[t] * b.y;
            }
        }
    }
    float dr = dinv[node];
    union { float2 f2; __half2 h2[2]; } u;
    u.h2[0] = __floats2half2_rn(dr * ax, dr * ay);
    u.h2[1] = __floats2half2_rn(dr * az, dr * aw);
    if constexpr (!FUSE_GEMM) {
        *(float2*)(xout + ((size_t)node << 6) + (ql << 2)) = u.f2;
    } else {
        __shared__ _Float16 tcl[16 * 72];   // 16 rows, stride 72 halves (2.3KB)
        // row r_loc = wib*4+q, channels 4ql..4ql+3
        *(float2*)(void*)&tcl[((wib << 2) + q) * 72 + (ql << 2)] = u.f2;
        __syncthreads();
        // ---- fused MFMA GEMM for this block's 16-row tile ----
        // A-frag: A[m=lane&15][k=quad*8+i]; B-frag: B[k][n=lane&15] from
        // transposed whc[j][n][k]; C/D: col=lane&15, row=quad*4+reg.
        // wave wib handles output cols [16*wib, 16*wib+16).
        const int mbase = blockIdx.x << 4;
        const __half* gsrc[3] = {x0, x1, xin};   // xh, tA, tB
        const size_t abase = ((size_t)(mbase + ql) << 6) + (q << 3);
        f32x4 acc = {};
#pragma unroll
        for (int j = 0; j < 4; ++j) {
#pragma unroll
            for (int kk = 0; kk < 64; kk += 32) {
                half8 af;
                if (j < 3)
                    af = *(const half8*)(const void*)(gsrc[j] + abase + kk);
                else
                    af = *(const half8*)(const void*)&tcl[ql * 72 + (q << 3) + kk];
                const _Float16* wb = whc + (j << 12) + (((wib << 4) + ql) << 6)
                                         + (q << 3) + kk;
                half8 bf = *(const half8*)(const void*)wb;
                acc = __builtin_amdgcn_mfma_f32_16x16x32_f16(af, bf, acc, 0, 0, 0);
            }
        }
#pragma unroll
        for (int i = 0; i < 4; ++i) {
            int r = mbase + (q << 2) + i;
            out[((size_t)r << 6) + (wib << 4) + ql] = acc[i];
        }
    }
}

extern "C" void kernel_launch(void* const* d_in, const int* in_sizes, int n_in,
                              void* d_out, int out_size, void* d_ws, size_t ws_size,
                              hipStream_t stream) {
    const float* x  = (const float*)d_in[0];
    const int*   ei = (const int*)d_in[1];   // row = ei[0..E), col = ei[E..2E)
    const float* ew = (const float*)d_in[2];
    const float* tf = (const float*)d_in[3];
    const float* tb = (const float*)d_in[4];
    float* out = (float*)d_out;

    const int* row = ei;
    const int* col = ei + N_EDGES;

    // workspace layout (4B words), total ~46 MB
    const int NROWS_PAD = NPART * 256;   // 50176
    float* ws = (float*)d_ws;
    size_t off = 0;
    int*    percur = (int*)(ws + off); off += 256;
    uint2*  pedges = (uint2*)(ws + off); off += (size_t)NPART * CAPP * 2;
    unsigned int* bkt = (unsigned int*)(ws + off); off += (size_t)NROWS_PAD * CAP;
    int*    cnt  = (int*)(ws + off); off += NROWS_PAD;
    float*  dinv = ws + off; off += NROWS_PAD;
    __half* xh   = (__half*)(ws + off); off += (size_t)N_NODES * C / 2;
    __half* tA   = (__half*)(ws + off); off += (size_t)N_NODES * C / 2;
    __half* tB   = (__half*)(ws + off); off += (size_t)N_NODES * C / 2;
    __half* tC   = (__half*)(ws + off); off += (size_t)N_NODES * C / 2;
    _Float16* whc = (_Float16*)(ws + off); off += 4 * 64 * 64 / 2;

    hipMemsetAsync(percur, 0, NPART * sizeof(int), stream);

    scatter2_kernel<<<NEB + XH_BLOCKS + CW_BLOCKS, 1024, 0, stream>>>(
        row, col, ew, percur, pedges, x, xh, tf, tb, whc);
    build_kernel<<<NPART, 1024, 0, stream>>>(pedges, percur, bkt, cnt, dinv);

    const int PB = N_NODES / 16;   // 3125 blocks, 16 nodes each (exact)
    prop_kernel<true,  false><<<PB, 256, 0, stream>>>(
        xh, tA, cnt, bkt, dinv, nullptr, nullptr, nullptr, nullptr);   // tx1
    prop_kernel<false, false><<<PB, 256, 0, stream>>>(
        tA, tB, cnt, bkt, dinv, nullptr, nullptr, nullptr, nullptr);   // tx2
    prop_kernel<false, true><<<PB, 256, 0, stream>>>(
        tB, tC, cnt, bkt, dinv, xh, tA, whc, out);                     // tx3+gemm
}